// Round 4
// baseline (161.870 us; speedup 1.0000x reference)
//
#include <hip/hip_runtime.h>
#include <hip/hip_bf16.h>
#include <math.h>

#define BB 4
#define CC 128
#define HH 128
#define WW 128
#define OO 256
#define HWP 16384   // H*W

typedef __attribute__((ext_vector_type(8))) _Float16 half8;   // f16x8 MFMA frag
typedef __attribute__((ext_vector_type(2))) _Float16 half2t;  // v_dot2 operand
typedef __attribute__((ext_vector_type(4))) float floatx4;    // MFMA C/D frag

__device__ inline half2t u2h2(unsigned int u) {
  union { unsigned int i; half2t h; } z; z.i = u; return z.h;
}
__device__ inline unsigned short f2h_bits(float f) {
  union { _Float16 h; unsigned short s; } z; z.h = (_Float16)f; return z.s;
}

// bilinear blend for 2 channels packed in one dword per corner
__device__ inline void blend2(unsigned int a00w, unsigned int a01w,
                              unsigned int a10w, unsigned int a11w,
                              half2t wt, half2t wb, float wk0, float wk1,
                              float& acc0, float& acc1) {
  unsigned int tl = __builtin_amdgcn_perm(a01w, a00w, 0x05040100u);
  unsigned int th = __builtin_amdgcn_perm(a01w, a00w, 0x07060302u);
  unsigned int bl = __builtin_amdgcn_perm(a11w, a10w, 0x05040100u);
  unsigned int bh = __builtin_amdgcn_perm(a11w, a10w, 0x07060302u);
  float v0 = __builtin_amdgcn_fdot2(u2h2(bl), wb, __builtin_amdgcn_fdot2(u2h2(tl), wt, 0.f, false), false);
  float v1 = __builtin_amdgcn_fdot2(u2h2(bh), wb, __builtin_amdgcn_fdot2(u2h2(th), wt, 0.f, false), false);
  acc0 = fmaf(v0, wk0, acc0);
  acc1 = fmaf(v1, wk1, acc1);
}

// swizzled om slot (dword units within a 32-dword row)
__device__ inline int om_idx(int px, int o) {
  return (((o >> 2) ^ (px & 7)) << 2) | (o & 3);
}

// ---------------------------------------------------------------------------
// P1: fused NCHW->NHWC f16 transpose (z<4) + weight prep (z==4).
// float4 global loads (1KB/inst), uint4 stores.
// ---------------------------------------------------------------------------
__global__ __launch_bounds__(256) void k_transpose(const float* __restrict__ x,
                                                   const float* __restrict__ w_off,
                                                   const float* __restrict__ w_pw,
                                                   unsigned int* __restrict__ xh32,
                                                   _Float16* __restrict__ Ah,
                                                   _Float16* __restrict__ Apw) {
  int tid = threadIdx.x;
  if (blockIdx.z == 4) {
    int e = (blockIdx.x * 128 + blockIdx.y) * 256 + tid;
    if (e < 144 * 32 * 8) {   // offconv A: [kblk=144][o=32][8], k = t*128+c
      int kblk = e >> 8;
      int o = (e >> 3) & 31;
      int j = e & 7;
      int k = kblk * 8 + j;
      int t = k >> 7, c = k & 127;
      float w = (o < 27) ? w_off[(o * CC + c) * 9 + t] : 0.0f;
      Ah[e] = (_Float16)w;
    }
    int e2 = e - 144 * 32 * 8;
    if (e2 >= 0 && e2 < 16 * 256 * 8) {   // pw A: [cblk=16][o=256][8]
      int cblk = e2 >> 11;
      int o = (e2 >> 3) & 255;
      int j = e2 & 7;
      Apw[e2] = (_Float16)w_pw[o * CC + cblk * 8 + j];
    }
    return;
  }
  __shared__ float tile[32][132];   // [c'][w], 132 = 33*4 (16B-aligned rows)
  int ct = blockIdx.x;              // 32-channel chunk
  int h = blockIdx.y, b = blockIdx.z;
  int f4 = tid & 31;                // float4 column (128 w = 32 float4)
  int cl = tid >> 5;                // 8 channels per pass
#pragma unroll
  for (int i = 0; i < 4; i++) {
    int c = cl + i * 8;
    float4 v = *(const float4*)(x + ((size_t)(b * CC + ct * 32 + c) * HH + h) * WW + f4 * 4);
    *(float4*)&tile[c][f4 * 4] = v;
  }
  __syncthreads();
  int cg = tid & 3;                 // uint4 group: 8 channels
#pragma unroll
  for (int pass = 0; pass < 2; pass++) {
    int px = pass * 64 + (tid >> 2);
    unsigned int d0, d1, d2, d3;
    d0 = (unsigned int)f2h_bits(tile[cg * 8 + 0][px]) | ((unsigned int)f2h_bits(tile[cg * 8 + 1][px]) << 16);
    d1 = (unsigned int)f2h_bits(tile[cg * 8 + 2][px]) | ((unsigned int)f2h_bits(tile[cg * 8 + 3][px]) << 16);
    d2 = (unsigned int)f2h_bits(tile[cg * 8 + 4][px]) | ((unsigned int)f2h_bits(tile[cg * 8 + 5][px]) << 16);
    d3 = (unsigned int)f2h_bits(tile[cg * 8 + 6][px]) | ((unsigned int)f2h_bits(tile[cg * 8 + 7][px]) << 16);
    uint4 z; z.x = d0; z.y = d1; z.z = d2; z.w = d3;
    *(uint4*)(xh32 + (size_t)((b * HH + h) * WW + px) * 64 + ct * 16 + cg * 4) = z;
  }
}

// ---------------------------------------------------------------------------
// MEGA-FUSED, wave-local pipeline version.
// Block = 64 px of one row; wave owns 16 px end-to-end through A/prologue/B:
//  A: full-K offconv MFMA for own 16 px -> om_s (swizzled, wave-local)
//  prologue: own px bilinear tables (packed base|flags, wp pairs) — no barrier
//  B: 2ch/lane, per-(px,tap) 4 contiguous 256B corner loads (SGPR base via
//     readfirstlane), 2-bank software pipeline over 16 px -> val (swizzled)
//  ONE __syncthreads, then C: pointwise MFMA (two-pass mf to cap VGPR).
// ---------------------------------------------------------------------------
__global__ __launch_bounds__(256, 4) void k_fused(
    const _Float16* __restrict__ xh, const _Float16* __restrict__ Ah,
    const _Float16* __restrict__ Apw, const float* __restrict__ b_off,
    const float* __restrict__ w_dw, const float* __restrict__ b_dw,
    const float* __restrict__ bpw, float* __restrict__ out) {
  __shared__ float om_s[64][32];                    // swizzled rows
  __shared__ int s_packed[64][9];                   // base | dxf<<30 | dyf<<31
  __shared__ unsigned int s_wp[64][9][2];           // packed half2 weights
  __shared__ __align__(16) _Float16 val[64][128];   // XOR-swizzled dw output

  int tid = threadIdx.x;
  int bid = blockIdx.x;
  int n0 = ((bid & 7) * 128 + (bid >> 3)) * 64;   // XCD-contiguous bands
  int b = n0 >> 14;
  int h0 = (n0 >> 7) & 127;
  int wbase = n0 & 127;   // 0 or 64

  int wv = tid >> 6, lane = tid & 63;
  int n16 = lane & 15, quad = lane >> 4;

  // ---- Phase A: offconv, wave wv owns pixels [wv*16, wv*16+16), full K
  {
    int pxb = wv * 16;
    floatx4 acc0 = {}, acc1 = {};
    half8 zz = {};
#pragma unroll
    for (int t = 0; t < 9; t++) {
      int dy = t / 3 - 1, dx = t % 3 - 1;
      int hs = h0 + dy;
      bool hok = ((unsigned)hs < HH);
      int hsc = min(max(hs, 0), HH - 1);
      int wA = wbase + pxb + n16 + dx;
      bool okA = hok && ((unsigned)wA < WW);
      int wAc = min(max(wA, 0), WW - 1);
      size_t rowoff = (size_t)((b * HH + hsc) * WW + wAc) * CC + quad * 8;
#pragma unroll
      for (int cs = 0; cs < 4; cs++) {
        half8 bh = *(const half8*)(xh + rowoff + cs * 32);
        bh = okA ? bh : zz;
        int kblk = t * 16 + cs * 4 + quad;
        const _Float16* pa = Ah + (size_t)kblk * 256 + n16 * 8;
        half8 a0 = *(const half8*)pa;
        half8 a1 = *(const half8*)(pa + 128);
        __builtin_amdgcn_s_setprio(1);
        acc0 = __builtin_amdgcn_mfma_f32_16x16x32_f16(a0, bh, acc0, 0, 0, 0);
        acc1 = __builtin_amdgcn_mfma_f32_16x16x32_f16(a1, bh, acc1, 0, 0, 0);
        __builtin_amdgcn_s_setprio(0);
      }
    }
    int px = pxb + n16;
#pragma unroll
    for (int reg = 0; reg < 4; reg++) {
      int o0 = quad * 4 + reg;
      om_s[px][om_idx(px, o0)] = acc0[reg] + b_off[o0];
      int o1 = 16 + quad * 4 + reg;
      if (o1 < 27) om_s[px][om_idx(px, o1)] = acc1[reg] + b_off[o1];
    }
  }
  // NO barrier: om_s rows for this wave's px were written by this wave.

  // ---- Prologue (wave-local): bilinear tables for own 16 px
#pragma unroll
  for (int pass = 0; pass < 3; pass++) {
    int it = pass * 64 + lane;
    if (it < 144) {
      int pxl = it / 9;
      int k = it - pxl * 9;
      int px = wv * 16 + pxl;
      int w = wbase + px;
      float dyv = om_s[px][om_idx(px, 2 * k)];
      float dxv = om_s[px][om_idx(px, 2 * k + 1)];
      float mvv = om_s[px][om_idx(px, 18 + k)];
      mvv = 1.0f / (1.0f + __expf(-mvv));
      float py = (float)(h0 + k / 3 - 1) + dyv;
      float pxf = (float)(w + k % 3 - 1) + dxv;
      float y0f = floorf(py), x0f = floorf(pxf);
      float wy = py - y0f, wx = pxf - x0f;
      int y0 = (int)y0f, x0 = (int)x0f;
      int y1 = y0 + 1, x1 = x0 + 1;
      float v00 = (y0 >= 0 && y0 < HH && x0 >= 0 && x0 < WW) ? 1.f : 0.f;
      float v01 = (y0 >= 0 && y0 < HH && x1 >= 0 && x1 < WW) ? 1.f : 0.f;
      float v10 = (y1 >= 0 && y1 < HH && x0 >= 0 && x0 < WW) ? 1.f : 0.f;
      float v11 = (y1 >= 0 && y1 < HH && x1 >= 0 && x1 < WW) ? 1.f : 0.f;
      int y0c = min(max(y0, 0), HH - 1), y1c = min(max(y1, 0), HH - 1);
      int x0c = min(max(x0, 0), WW - 1), x1c = min(max(x1, 0), WW - 1);
      int base = ((b * HH + y0c) * WW + x0c) * CC;
      int dxf = (x1c > x0c) ? 1 : 0;
      int dyf = (y1c > y0c) ? 1 : 0;
      s_packed[px][k] = base | (dxf << 30) | (dyf << 31);
      float w00 = (1.f - wy) * (1.f - wx) * mvv * v00;
      float w01 = (1.f - wy) * wx * mvv * v01;
      float w10 = wy * (1.f - wx) * mvv * v10;
      float w11 = wy * wx * mvv * v11;
      s_wp[px][k][0] = (unsigned int)f2h_bits(w00) | ((unsigned int)f2h_bits(w01) << 16);
      s_wp[px][k][1] = (unsigned int)f2h_bits(w10) | ((unsigned int)f2h_bits(w11) << 16);
    }
  }
  // NO barrier: tables for this wave's px are wave-local; LDS is in-order.

  // ---- Phase B: sampling + depthwise; 2 channels/lane, 16 px per wave,
  //      2-bank software pipeline (issue px+1 while computing px).
  {
    int c0 = lane * 2;
    const unsigned short* xs = (const unsigned short*)xh;
    float wk0[9], wk1[9];
    {
      const float* wp_ = w_dw + c0 * 9;
#pragma unroll
      for (int k = 0; k < 9; k++) { wk0[k] = wp_[k]; wk1[k] = wp_[9 + k]; }
    }
    float2 bdp = *(const float2*)(b_dw + c0);

    unsigned int A00[9], A01[9], A10[9], A11[9];
    unsigned int B00[9], B01[9], B10[9], B11[9];

    auto issue = [&](int pxl, unsigned int* c00, unsigned int* c01,
                     unsigned int* c10, unsigned int* c11) {
      int px = wv * 16 + pxl;
#pragma unroll
      for (int k = 0; k < 9; k++) {
        int pk = __builtin_amdgcn_readfirstlane(s_packed[px][k]);
        int base = (pk & 0x3FFFFFFF) + c0;
        int dxs = (pk & 0x40000000) ? CC : 0;
        int dys = (pk & 0x80000000u) ? (WW * CC) : 0;
        c00[k] = *(const unsigned int*)(xs + base);
        c01[k] = *(const unsigned int*)(xs + base + dxs);
        c10[k] = *(const unsigned int*)(xs + base + dys);
        c11[k] = *(const unsigned int*)(xs + base + dys + dxs);
      }
    };
    auto compute = [&](int pxl, const unsigned int* c00, const unsigned int* c01,
                       const unsigned int* c10, const unsigned int* c11) {
      int px = wv * 16 + pxl;
      float a0 = 0.f, a1 = 0.f;
#pragma unroll
      for (int k = 0; k < 9; k++) {
        uint2 w2 = *(const uint2*)&s_wp[px][k][0];
        blend2(c00[k], c01[k], c10[k], c11[k], u2h2(w2.x), u2h2(w2.y),
               wk0[k], wk1[k], a0, a1);
      }
      unsigned int d = (unsigned int)f2h_bits(a0 + bdp.x) |
                       ((unsigned int)f2h_bits(a1 + bdp.y) << 16);
      int su = (lane >> 2) ^ (px & 7);
      *(unsigned int*)((char*)&val[px][0] + su * 16 + (lane & 3) * 4) = d;
    };

    issue(0, A00, A01, A10, A11);
#pragma unroll
    for (int i = 0; i < 16; i += 2) {
      issue(i + 1, B00, B01, B10, B11);
      compute(i, A00, A01, A10, A11);
      if (i + 2 < 16) issue(i + 2, A00, A01, A10, A11);
      compute(i + 1, B00, B01, B10, B11);
    }
  }
  __syncthreads();   // the only block-wide barrier

  // ---- Phase C: pointwise GEMM 256o x 64n x 128c; two-pass mf (VGPR cap)
  {
    int obase = wv * 64;
#pragma unroll
    for (int mh = 0; mh < 2; mh++) {
      floatx4 acc[2][4] = {};
#pragma unroll
      for (int cs = 0; cs < 4; cs++) {
        half8 af[2], bf[4];
#pragma unroll
        for (int mf = 0; mf < 2; mf++) {
          const _Float16* pa = Apw + ((size_t)(cs * 4 + quad) * 256 + obase + (mh * 2 + mf) * 16 + n16) * 8;
          af[mf] = *(const half8*)pa;
        }
#pragma unroll
        for (int nf = 0; nf < 4; nf++) {
          int row = nf * 16 + n16;
          int su = (cs * 4 + quad) ^ (row & 7);
          bf[nf] = *(const half8*)&val[row][su * 8];
        }
        __builtin_amdgcn_s_setprio(1);
#pragma unroll
        for (int mf = 0; mf < 2; mf++)
#pragma unroll
          for (int nf = 0; nf < 4; nf++)
            acc[mf][nf] = __builtin_amdgcn_mfma_f32_16x16x32_f16(af[mf], bf[nf], acc[mf][nf], 0, 0, 0);
        __builtin_amdgcn_s_setprio(0);
      }
#pragma unroll
      for (int mf = 0; mf < 2; mf++) {
#pragma unroll
        for (int reg = 0; reg < 4; reg++) {
          int o = obase + (mh * 2 + mf) * 16 + quad * 4 + reg;
          float bo = bpw[o];
#pragma unroll
          for (int nf = 0; nf < 4; nf++) {
            int n = n0 + nf * 16 + n16;
            int hw = n & 16383;
            out[((size_t)(b * OO + o) << 14) + hw] = acc[mf][nf][reg] + bo;
          }
        }
      }
    }
  }
}

// ---------------------------------------------------------------------------
extern "C" void kernel_launch(void* const* d_in, const int* in_sizes, int n_in,
                              void* d_out, int out_size, void* d_ws, size_t ws_size,
                              hipStream_t stream) {
  const float* x     = (const float*)d_in[0];
  const float* w_off = (const float*)d_in[1];
  const float* b_off = (const float*)d_in[2];
  const float* w_dw  = (const float*)d_in[3];
  const float* b_dw  = (const float*)d_in[4];
  const float* w_pw  = (const float*)d_in[5];
  const float* b_pw  = (const float*)d_in[6];
  float* out = (float*)d_out;
  float* ws  = (float*)d_ws;

  // ws layout (byte offsets):
  //   xh  : f16 NHWC, 8388608 elems = 16,777,216 B  at 0
  //   Ah  : f16 36864 elems                          at 16,777,216
  //   Apw : f16 65536 elems                          after Ah
  _Float16* xh  = (_Float16*)ws;
  _Float16* Ah  = (_Float16*)((char*)ws + 16777216);
  _Float16* Apw = Ah + 36864;

  k_transpose<<<dim3(4, 128, 5), 256, 0, stream>>>(x, w_off, w_pw,
                                                   (unsigned int*)xh, Ah, Apw);
  k_fused<<<1024, 256, 0, stream>>>(xh, Ah, Apw, b_off, w_dw, b_dw, b_pw, out);
}

// Round 5
// 157.707 us; speedup vs baseline: 1.0264x; 1.0264x over previous
//
#include <hip/hip_runtime.h>
#include <hip/hip_bf16.h>
#include <math.h>

#define BB 4
#define CC 128
#define HH 128
#define WW 128
#define OO 256
#define HWP 16384   // H*W

typedef __attribute__((ext_vector_type(8))) _Float16 half8;   // f16x8 MFMA frag
typedef __attribute__((ext_vector_type(2))) _Float16 half2t;  // v_dot2 operand
typedef __attribute__((ext_vector_type(4))) float floatx4;    // MFMA C/D frag

__device__ inline half2t u2h2(unsigned int u) {
  union { unsigned int i; half2t h; } z; z.i = u; return z.h;
}
__device__ inline unsigned short f2h_bits(float f) {
  union { _Float16 h; unsigned short s; } z; z.h = (_Float16)f; return z.s;
}

// bilinear blend for 2 channels packed in one dword per corner
__device__ inline void blend2(unsigned int a00w, unsigned int a01w,
                              unsigned int a10w, unsigned int a11w,
                              half2t wt, half2t wb, float wk0, float wk1,
                              float& acc0, float& acc1) {
  unsigned int tl = __builtin_amdgcn_perm(a01w, a00w, 0x05040100u);
  unsigned int th = __builtin_amdgcn_perm(a01w, a00w, 0x07060302u);
  unsigned int bl = __builtin_amdgcn_perm(a11w, a10w, 0x05040100u);
  unsigned int bh = __builtin_amdgcn_perm(a11w, a10w, 0x07060302u);
  float v0 = __builtin_amdgcn_fdot2(u2h2(bl), wb, __builtin_amdgcn_fdot2(u2h2(tl), wt, 0.f, false), false);
  float v1 = __builtin_amdgcn_fdot2(u2h2(bh), wb, __builtin_amdgcn_fdot2(u2h2(th), wt, 0.f, false), false);
  acc0 = fmaf(v0, wk0, acc0);
  acc1 = fmaf(v1, wk1, acc1);
}

// swizzled om slot (dword units within a 32-dword row)
__device__ inline int om_idx(int px, int o) {
  return (((o >> 2) ^ (px & 7)) << 2) | (o & 3);
}

// ---------------------------------------------------------------------------
// P1: NCHW->NHWC f16 transpose (bid<1024) + weight prep (bid>=1024).
// Transpose block = (b, h, half-row): 128ch x 64w.
//  Load: 2 coalesced float4 rows (c, c+1) -> pack channel-pair u32.
//  LDS: u32 tile[64][64], XOR-unit swizzle su=(cp>>2)^wq:
//       writes 2-way-free b32, reads conflict-free b128.
//  Store: 16 lanes x 16B = full 256B cacheline per pixel.
// ---------------------------------------------------------------------------
__global__ __launch_bounds__(256) void k_transpose(const float* __restrict__ x,
                                                   const float* __restrict__ w_off,
                                                   const float* __restrict__ w_pw,
                                                   unsigned int* __restrict__ xh32,
                                                   _Float16* __restrict__ Ah,
                                                   _Float16* __restrict__ Apw) {
  int tid = threadIdx.x;
  int bid = blockIdx.x;
  if (bid >= 1024) {
    int e = (bid - 1024) * 256 + tid;
    if (e < 144 * 32 * 8) {   // offconv A: [kblk=144][o=32][8], k = t*128+c
      int kblk = e >> 8;
      int o = (e >> 3) & 31;
      int j = e & 7;
      int k = kblk * 8 + j;
      int t = k >> 7, c = k & 127;
      float w = (o < 27) ? w_off[(o * CC + c) * 9 + t] : 0.0f;
      Ah[e] = (_Float16)w;
    }
    int e2 = e - 144 * 32 * 8;
    if (e2 >= 0 && e2 < 16 * 256 * 8) {   // pw A: [cblk=16][o=256][8]
      int cblk = e2 >> 11;
      int o = (e2 >> 3) & 255;
      int j = e2 & 7;
      Apw[e2] = (_Float16)w_pw[o * CC + cblk * 8 + j];
    }
    return;
  }
  __shared__ __align__(16) unsigned int tile32[64][64];   // [w][swizzled cpair]
  int half = bid & 1;
  int h = (bid >> 1) & 127;
  int b = bid >> 8;
  int wq = tid & 15;        // w quad: 16 lanes x 4 f32 = 64 w
  int cb = tid >> 4;        // 16 channel-pair groups
#pragma unroll
  for (int i = 0; i < 4; i++) {
    int c0 = i * 32 + cb * 2;
    const float* p0 = x + ((size_t)(b * CC + c0) * HH + h) * WW + half * 64 + wq * 4;
    float4 v0 = *(const float4*)p0;
    float4 v1 = *(const float4*)(p0 + HWP);
    const float* f0 = &v0.x;
    const float* f1 = &v1.x;
    int cp = i * 16 + cb;
    int su = (cp >> 2) ^ wq;
#pragma unroll
    for (int j = 0; j < 4; j++) {
      unsigned int pk = (unsigned int)f2h_bits(f0[j]) | ((unsigned int)f2h_bits(f1[j]) << 16);
      tile32[wq * 4 + j][su * 4 + (cp & 3)] = pk;
    }
  }
  __syncthreads();
  int cg = tid & 15;        // 16B unit = 8 channels
#pragma unroll
  for (int p = 0; p < 4; p++) {
    int w = p * 16 + (tid >> 4);
    int su = cg ^ ((w >> 2) & 15);
    uint4 v = *(const uint4*)&tile32[w][su * 4];
    *(uint4*)(xh32 + (size_t)((b * HH + h) * WW + half * 64 + w) * 64 + cg * 4) = v;
  }
}

// ---------------------------------------------------------------------------
// MEGA-FUSED, occupancy-first version: 32 px/block, grid 2048 (8 blocks/CU).
//  Phase A: waves 0,1 each run full-K offconv MFMA for 16 px -> om_s.
//  barrier. Prologue: wave-local bilinear tables for own 8 px.
//  Phase B: wave owns 8 px; 2ch/lane dword gathers via SGPR (readfirstlane)
//           table bases; plain loop, TLP (up to 32 waves/CU) hides latency.
//  barrier. Phase C: pointwise 256o x 32n x 128c MFMA from swizzled val LDS.
// ---------------------------------------------------------------------------
__global__ __launch_bounds__(256, 4) void k_fused(
    const _Float16* __restrict__ xh, const _Float16* __restrict__ Ah,
    const _Float16* __restrict__ Apw, const float* __restrict__ b_off,
    const float* __restrict__ w_dw, const float* __restrict__ b_dw,
    const float* __restrict__ bpw, float* __restrict__ out) {
  __shared__ float om_s[32][32];                    // swizzled rows
  __shared__ int s_packed[32][9];                   // base | dxf<<30 | dyf<<31
  __shared__ unsigned int s_wp[32][9][2];           // packed half2 weights
  __shared__ __align__(16) _Float16 val[32][128];   // XOR-swizzled dw output

  int tid = threadIdx.x;
  int bid = blockIdx.x;
  int n0 = ((bid & 7) * 256 + (bid >> 3)) * 32;   // XCD-contiguous bands
  int b = n0 >> 14;
  int h0 = (n0 >> 7) & 127;
  int wbase = n0 & 127;   // 0,32,64,96

  int wv = tid >> 6, lane = tid & 63;
  int n16 = lane & 15, quad = lane >> 4;

  // ---- Phase A: offconv; waves 0,1 own px tiles [wv*16, wv*16+16), full K
  if (wv < 2) {
    int pxb = wv * 16;
    floatx4 acc0 = {}, acc1 = {};
    half8 zz = {};
#pragma unroll
    for (int t = 0; t < 9; t++) {
      int dy = t / 3 - 1, dx = t % 3 - 1;
      int hs = h0 + dy;
      bool hok = ((unsigned)hs < HH);
      int hsc = min(max(hs, 0), HH - 1);
      int wA = wbase + pxb + n16 + dx;
      bool okA = hok && ((unsigned)wA < WW);
      int wAc = min(max(wA, 0), WW - 1);
      size_t rowoff = (size_t)((b * HH + hsc) * WW + wAc) * CC + quad * 8;
#pragma unroll
      for (int cs = 0; cs < 4; cs++) {
        half8 bh = *(const half8*)(xh + rowoff + cs * 32);
        bh = okA ? bh : zz;
        int kblk = t * 16 + cs * 4 + quad;
        const _Float16* pa = Ah + (size_t)kblk * 256 + n16 * 8;
        half8 a0 = *(const half8*)pa;
        half8 a1 = *(const half8*)(pa + 128);
        __builtin_amdgcn_s_setprio(1);
        acc0 = __builtin_amdgcn_mfma_f32_16x16x32_f16(a0, bh, acc0, 0, 0, 0);
        acc1 = __builtin_amdgcn_mfma_f32_16x16x32_f16(a1, bh, acc1, 0, 0, 0);
        __builtin_amdgcn_s_setprio(0);
      }
    }
    int px = pxb + n16;
#pragma unroll
    for (int reg = 0; reg < 4; reg++) {
      int o0 = quad * 4 + reg;
      om_s[px][om_idx(px, o0)] = acc0[reg] + b_off[o0];
      int o1 = 16 + quad * 4 + reg;
      if (o1 < 27) om_s[px][om_idx(px, o1)] = acc1[reg] + b_off[o1];
    }
  }
  __syncthreads();

  // ---- Prologue (wave-local): bilinear tables for own 8 px
#pragma unroll
  for (int pass = 0; pass < 2; pass++) {
    int it = pass * 64 + lane;
    if (it < 72) {
      int pxl = it / 9;
      int k = it - pxl * 9;
      int px = wv * 8 + pxl;
      int w = wbase + px;
      float dyv = om_s[px][om_idx(px, 2 * k)];
      float dxv = om_s[px][om_idx(px, 2 * k + 1)];
      float mvv = om_s[px][om_idx(px, 18 + k)];
      mvv = 1.0f / (1.0f + __expf(-mvv));
      float py = (float)(h0 + k / 3 - 1) + dyv;
      float pxf = (float)(w + k % 3 - 1) + dxv;
      float y0f = floorf(py), x0f = floorf(pxf);
      float wy = py - y0f, wx = pxf - x0f;
      int y0 = (int)y0f, x0 = (int)x0f;
      int y1 = y0 + 1, x1 = x0 + 1;
      float v00 = (y0 >= 0 && y0 < HH && x0 >= 0 && x0 < WW) ? 1.f : 0.f;
      float v01 = (y0 >= 0 && y0 < HH && x1 >= 0 && x1 < WW) ? 1.f : 0.f;
      float v10 = (y1 >= 0 && y1 < HH && x0 >= 0 && x0 < WW) ? 1.f : 0.f;
      float v11 = (y1 >= 0 && y1 < HH && x1 >= 0 && x1 < WW) ? 1.f : 0.f;
      int y0c = min(max(y0, 0), HH - 1), y1c = min(max(y1, 0), HH - 1);
      int x0c = min(max(x0, 0), WW - 1), x1c = min(max(x1, 0), WW - 1);
      int base = ((b * HH + y0c) * WW + x0c) * CC;
      int dxf = (x1c > x0c) ? 1 : 0;
      int dyf = (y1c > y0c) ? 1 : 0;
      s_packed[px][k] = base | (dxf << 30) | (dyf << 31);
      float w00 = (1.f - wy) * (1.f - wx) * mvv * v00;
      float w01 = (1.f - wy) * wx * mvv * v01;
      float w10 = wy * (1.f - wx) * mvv * v10;
      float w11 = wy * wx * mvv * v11;
      s_wp[px][k][0] = (unsigned int)f2h_bits(w00) | ((unsigned int)f2h_bits(w01) << 16);
      s_wp[px][k][1] = (unsigned int)f2h_bits(w10) | ((unsigned int)f2h_bits(w11) << 16);
    }
  }
  // NO barrier: tables for this wave's px are wave-local; LDS is in-order.

  // ---- Phase B: sampling + depthwise; 2 channels/lane, 8 px per wave
  {
    int c0 = lane * 2;
    const unsigned short* xs = (const unsigned short*)xh;
    float wk0[9], wk1[9];
    {
      const float* wp_ = w_dw + c0 * 9;
#pragma unroll
      for (int k = 0; k < 9; k++) { wk0[k] = wp_[k]; wk1[k] = wp_[9 + k]; }
    }
    float2 bdp = *(const float2*)(b_dw + c0);

#pragma unroll
    for (int p = 0; p < 8; p++) {
      int px = wv * 8 + p;
      unsigned int C00[9], C01[9], C10[9], C11[9];
#pragma unroll
      for (int k = 0; k < 9; k++) {
        int pk = __builtin_amdgcn_readfirstlane(s_packed[px][k]);
        int base = (pk & 0x3FFFFFFF) + c0;
        int dxs = (pk & 0x40000000) ? CC : 0;
        int dys = (pk & 0x80000000u) ? (WW * CC) : 0;
        C00[k] = *(const unsigned int*)(xs + base);
        C01[k] = *(const unsigned int*)(xs + base + dxs);
        C10[k] = *(const unsigned int*)(xs + base + dys);
        C11[k] = *(const unsigned int*)(xs + base + dys + dxs);
      }
      float a0 = 0.f, a1 = 0.f;
#pragma unroll
      for (int k = 0; k < 9; k++) {
        uint2 w2 = *(const uint2*)&s_wp[px][k][0];
        blend2(C00[k], C01[k], C10[k], C11[k], u2h2(w2.x), u2h2(w2.y),
               wk0[k], wk1[k], a0, a1);
      }
      unsigned int d = (unsigned int)f2h_bits(a0 + bdp.x) |
                       ((unsigned int)f2h_bits(a1 + bdp.y) << 16);
      int su = (lane >> 2) ^ (px & 7);
      *(unsigned int*)((char*)&val[px][0] + su * 16 + (lane & 3) * 4) = d;
    }
  }
  __syncthreads();

  // ---- Phase C: pointwise GEMM 256o x 32n x 128c; wave wv -> o [wv*64, +64)
  {
    int obase = wv * 64;
    floatx4 acc[4][2] = {};   // [mf][nf]
#pragma unroll
    for (int cs = 0; cs < 4; cs++) {
      half8 af[4], bf[2];
#pragma unroll
      for (int mf = 0; mf < 4; mf++) {
        const _Float16* pa = Apw + ((size_t)(cs * 4 + quad) * 256 + obase + mf * 16 + n16) * 8;
        af[mf] = *(const half8*)pa;
      }
#pragma unroll
      for (int nf = 0; nf < 2; nf++) {
        int row = nf * 16 + n16;
        int su = (cs * 4 + quad) ^ (row & 7);
        bf[nf] = *(const half8*)&val[row][su * 8];
      }
      __builtin_amdgcn_s_setprio(1);
#pragma unroll
      for (int mf = 0; mf < 4; mf++)
#pragma unroll
        for (int nf = 0; nf < 2; nf++)
          acc[mf][nf] = __builtin_amdgcn_mfma_f32_16x16x32_f16(af[mf], bf[nf], acc[mf][nf], 0, 0, 0);
      __builtin_amdgcn_s_setprio(0);
    }
#pragma unroll
    for (int mf = 0; mf < 4; mf++) {
#pragma unroll
      for (int reg = 0; reg < 4; reg++) {
        int o = obase + mf * 16 + quad * 4 + reg;
        float bo = bpw[o];
#pragma unroll
        for (int nf = 0; nf < 2; nf++) {
          int n = n0 + nf * 16 + n16;
          int hw = n & 16383;
          out[((size_t)(b * OO + o) << 14) + hw] = acc[mf][nf][reg] + bo;
        }
      }
    }
  }
}

// ---------------------------------------------------------------------------
extern "C" void kernel_launch(void* const* d_in, const int* in_sizes, int n_in,
                              void* d_out, int out_size, void* d_ws, size_t ws_size,
                              hipStream_t stream) {
  const float* x     = (const float*)d_in[0];
  const float* w_off = (const float*)d_in[1];
  const float* b_off = (const float*)d_in[2];
  const float* w_dw  = (const float*)d_in[3];
  const float* b_dw  = (const float*)d_in[4];
  const float* w_pw  = (const float*)d_in[5];
  const float* b_pw  = (const float*)d_in[6];
  float* out = (float*)d_out;
  float* ws  = (float*)d_ws;

  // ws layout (byte offsets):
  //   xh  : f16 NHWC, 8388608 elems = 16,777,216 B  at 0
  //   Ah  : f16 36864 elems                          at 16,777,216
  //   Apw : f16 65536 elems                          after Ah
  _Float16* xh  = (_Float16*)ws;
  _Float16* Ah  = (_Float16*)((char*)ws + 16777216);
  _Float16* Apw = Ah + 36864;

  k_transpose<<<1536, 256, 0, stream>>>(x, w_off, w_pw,
                                        (unsigned int*)xh, Ah, Apw);
  k_fused<<<2048, 256, 0, stream>>>(xh, Ah, Apw, b_off, w_dw, b_dw, b_pw, out);
}